// Round 5
// baseline (235.468 us; speedup 1.0000x reference)
//
#include <hip/hip_runtime.h>

#define B_  4
#define T_  2048
#define C_  384
#define NH_ 6
#define HS_ 64
#define M_  (B_*T_)   // 8192 rows

typedef float floatx4 __attribute__((ext_vector_type(4)));
typedef __bf16 bf16x8 __attribute__((ext_vector_type(8)));
typedef unsigned short ushort_t;
typedef unsigned short ushortx8 __attribute__((ext_vector_type(8)));
typedef unsigned short ushortx4 __attribute__((ext_vector_type(4)));

__device__ __forceinline__ ushort_t f2bf(float f) {
    unsigned u = __builtin_bit_cast(unsigned, f);
    unsigned r = (u + 0x7FFFu + ((u >> 16) & 1u)) >> 16;   // RNE
    return (ushort_t)r;
}

// ---------------------------------------------------------------------------
// prep: W transpose-casts only (x-cast is fused into qkv_gemm staging).
// 64x64 tiles: 4 matrices x 36 tiles = 144 blocks.
// ---------------------------------------------------------------------------
__global__ __launch_bounds__(256) void prep(
    const float* __restrict__ Wq, const float* __restrict__ Wk,
    const float* __restrict__ Wv, const float* __restrict__ Wo,
    ushort_t* __restrict__ Wtq, ushort_t* __restrict__ Wtk,
    ushort_t* __restrict__ Wtv, ushort_t* __restrict__ Wto)
{
    __shared__ float Ls[64][65];
    const int tid = threadIdx.x;
    const int idx = blockIdx.x;
    const int z = idx / 36, rest = idx % 36;
    const float* __restrict__ W = (z == 0) ? Wq : (z == 1) ? Wk : (z == 2) ? Wv : Wo;
    ushort_t* __restrict__ Wt   = (z == 0) ? Wtq : (z == 1) ? Wtk : (z == 2) ? Wtv : Wto;
    const int k0 = (rest / 6) * 64, n0 = (rest % 6) * 64;

    #pragma unroll
    for (int p = 0; p < 4; ++p) {
        const int kk = p * 16 + (tid >> 4);
        const int nn = (tid & 15) * 4;
        const float4 v = *(const float4*)&W[(size_t)(k0 + kk) * 384 + n0 + nn];
        Ls[kk][nn] = v.x; Ls[kk][nn + 1] = v.y; Ls[kk][nn + 2] = v.z; Ls[kk][nn + 3] = v.w;
    }
    __syncthreads();
    #pragma unroll
    for (int p = 0; p < 4; ++p) {
        const int n = p * 16 + (tid >> 4);
        const int kc = (tid & 15) * 4;
        ushortx4 pk;
        #pragma unroll
        for (int t = 0; t < 4; ++t) pk[t] = f2bf(Ls[kc + t][n]);
        *(ushortx4*)&Wt[(size_t)(n0 + n) * 384 + k0 + kc] = pk;
    }
}

// ---------------------------------------------------------------------------
// Fused QKV MFMA GEMM; A-tile staging converts x fp32 -> bf16 on the fly.
// ---------------------------------------------------------------------------
__global__ __launch_bounds__(256) void qkv_gemm(
    const float* __restrict__ x,
    const ushort_t* __restrict__ Wtq, const ushort_t* __restrict__ Wtk,
    const ushort_t* __restrict__ Wtv,
    const float* __restrict__ bq, const float* __restrict__ bk, const float* __restrict__ bv,
    ushort_t* __restrict__ Qb, ushort_t* __restrict__ Kb, ushort_t* __restrict__ Vtb)
{
    __shared__ ushort_t Sm[2 * 128 * 32];

    const int tid  = threadIdx.x;
    const int lane = tid & 63;
    const int wv   = tid >> 6;
    const int m    = lane & 15;
    const int quad = lane >> 4;

    const int t0 = blockIdx.x * 128;
    const int n0 = blockIdx.y * 128;
    const int which = n0 / 384;
    const int n_in0 = n0 % 384;
    const bool isV = (which == 2);

    const ushort_t* __restrict__ Wt = (which == 0) ? Wtq : (which == 1) ? Wtk : Wtv;

    const int aOff = isV ? 0 : 4096;
    const int bOff = isV ? 4096 : 0;
    const int a0 = (wv & 1) * 64;
    const int b0 = (wv >> 1) * 64;

    floatx4 acc[4][4];
    #pragma unroll
    for (int i = 0; i < 4; ++i)
        #pragma unroll
        for (int j = 0; j < 4; ++j) acc[i][j] = (floatx4){0.f, 0.f, 0.f, 0.f};

    for (int k0 = 0; k0 < 384; k0 += 32) {
        __syncthreads();
        #pragma unroll
        for (int u = 0; u < 2; ++u) {
            const int e = tid + u * 256;
            const int r = e >> 2, c = (e & 3) * 8;
            const float4 xa = *(const float4*)&x[(size_t)(t0 + r) * 384 + k0 + c];
            const float4 xc = *(const float4*)&x[(size_t)(t0 + r) * 384 + k0 + c + 4];
            ushortx8 xp;
            xp[0] = f2bf(xa.x); xp[1] = f2bf(xa.y); xp[2] = f2bf(xa.z); xp[3] = f2bf(xa.w);
            xp[4] = f2bf(xc.x); xp[5] = f2bf(xc.y); xp[6] = f2bf(xc.z); xp[7] = f2bf(xc.w);
            *(ushortx8*)&Sm[r * 32 + c] = xp;
            *(ushortx8*)&Sm[4096 + r * 32 + c] =
                *(const ushortx8*)&Wt[(size_t)(n_in0 + r) * 384 + k0 + c];
        }
        __syncthreads();

        bf16x8 fA[4], fB[4];
        #pragma unroll
        for (int i = 0; i < 4; ++i)
            fA[i] = *(const bf16x8*)&Sm[aOff + (a0 + i * 16 + m) * 32 + quad * 8];
        #pragma unroll
        for (int j = 0; j < 4; ++j)
            fB[j] = *(const bf16x8*)&Sm[bOff + (b0 + j * 16 + m) * 32 + quad * 8];
        #pragma unroll
        for (int i = 0; i < 4; ++i)
            #pragma unroll
            for (int j = 0; j < 4; ++j)
                acc[i][j] = __builtin_amdgcn_mfma_f32_16x16x32_bf16(fA[i], fB[j], acc[i][j], 0, 0, 0);
    }

    if (!isV) {
        ushort_t* __restrict__ out = (which == 0) ? Qb : Kb;
        const float* __restrict__ bias = (which == 0) ? bq : bk;
        const float scale = (which == 0) ? 0.125f : 1.0f;
        #pragma unroll
        for (int i = 0; i < 4; ++i) {
            const int n_base = n_in0 + a0 + i * 16 + quad * 4;
            const int h = n_base >> 6, d0 = n_base & 63;
            #pragma unroll
            for (int j = 0; j < 4; ++j) {
                const int tg = t0 + b0 + j * 16 + m;
                const int b = tg >> 11, tb = tg & (T_ - 1);
                ushortx4 pk;
                #pragma unroll
                for (int r = 0; r < 4; ++r)
                    pk[r] = f2bf((acc[i][j][r] + bias[n_base + r]) * scale);
                *(ushortx4*)&out[(((size_t)(b * NH_ + h)) * T_ + tb) * HS_ + d0] = pk;
            }
        }
    } else {
        #pragma unroll
        for (int i = 0; i < 4; ++i) {
            const int tg0 = t0 + a0 + i * 16 + quad * 4;
            const int b = tg0 >> 11, tb0 = tg0 & (T_ - 1);
            #pragma unroll
            for (int j = 0; j < 4; ++j) {
                const int n_l = n_in0 + b0 + j * 16 + m;
                const int h = n_l >> 6, d = n_l & 63;
                const float bb = bv[n_l];
                ushortx4 pk;
                #pragma unroll
                for (int r = 0; r < 4; ++r) pk[r] = f2bf(acc[i][j][r] + bb);
                *(ushortx4*)&Vtb[(((size_t)(b * NH_ + h)) * HS_ + d) * T_ + tb0] = pk;
            }
        }
    }
}

// ---------------------------------------------------------------------------
// Output projection MFMA GEMM (unchanged).
// ---------------------------------------------------------------------------
__global__ __launch_bounds__(256) void proj_gemm(
    const ushort_t* __restrict__ ctxb,
    const ushort_t* __restrict__ Wto,
    const float* __restrict__ bo,
    float* __restrict__ out)
{
    __shared__ ushort_t Sm[2 * 128 * 32];

    const int tid  = threadIdx.x;
    const int lane = tid & 63;
    const int wv   = tid >> 6;
    const int m    = lane & 15;
    const int quad = lane >> 4;

    const int t0 = blockIdx.x * 128;
    const int n0 = blockIdx.y * 128;
    const int a0 = (wv & 1) * 64;
    const int b0 = (wv >> 1) * 64;

    floatx4 acc[4][4];
    #pragma unroll
    for (int i = 0; i < 4; ++i)
        #pragma unroll
        for (int j = 0; j < 4; ++j) acc[i][j] = (floatx4){0.f, 0.f, 0.f, 0.f};

    for (int k0 = 0; k0 < 384; k0 += 32) {
        __syncthreads();
        #pragma unroll
        for (int u = 0; u < 2; ++u) {
            const int e = tid + u * 256;
            const int r = e >> 2, c = (e & 3) * 8;
            *(ushortx8*)&Sm[r * 32 + c] =
                *(const ushortx8*)&ctxb[(size_t)(t0 + r) * 384 + k0 + c];
            *(ushortx8*)&Sm[4096 + r * 32 + c] =
                *(const ushortx8*)&Wto[(size_t)(n0 + r) * 384 + k0 + c];
        }
        __syncthreads();

        bf16x8 fA[4], fB[4];
        #pragma unroll
        for (int i = 0; i < 4; ++i)
            fA[i] = *(const bf16x8*)&Sm[4096 + (a0 + i * 16 + m) * 32 + quad * 8];
        #pragma unroll
        for (int j = 0; j < 4; ++j)
            fB[j] = *(const bf16x8*)&Sm[(b0 + j * 16 + m) * 32 + quad * 8];
        #pragma unroll
        for (int i = 0; i < 4; ++i)
            #pragma unroll
            for (int j = 0; j < 4; ++j)
                acc[i][j] = __builtin_amdgcn_mfma_f32_16x16x32_bf16(fA[i], fB[j], acc[i][j], 0, 0, 0);
    }

    #pragma unroll
    for (int i = 0; i < 4; ++i) {
        const int n_base = n0 + a0 + i * 16 + quad * 4;
        const float4 bb = *(const float4*)&bo[n_base];
        #pragma unroll
        for (int j = 0; j < 4; ++j) {
            const int tg = t0 + b0 + j * 16 + m;
            float4 o;
            o.x = acc[i][j][0] + bb.x;
            o.y = acc[i][j][1] + bb.y;
            o.z = acc[i][j][2] + bb.z;
            o.w = acc[i][j][3] + bb.w;
            *(float4*)&out[(size_t)tg * 384 + n_base] = o;
        }
    }
}

// ---------------------------------------------------------------------------
// Barrier-free flash attention.
//   Wave = (16-row q-tile, key-split parity). Block = 4 waves:
//   waves 0,1 -> heavy tile 127-pr (splits 0,1); waves 2,3 -> light tile pr.
//   Fixed-max softmax is linear in k-tiles -> key-split partials combine by
//   plain addition of (O, l) at the epilogue (one __syncthreads per block).
//   All Q/K/V fragments are direct coalesced b128 GLOBAL loads (K=[t][d],
//   Vt=[d][t] make every fragment 8 consecutive bf16 per lane). LDS holds
//   only the per-wave P transpose (stride 72: 2-way = free) + combine bufs.
// ---------------------------------------------------------------------------
__global__ __launch_bounds__(256, 4) void attn_mfma(
    const ushort_t* __restrict__ Q,    // [BH][T][64] bf16, pre-scaled 1/8
    const ushort_t* __restrict__ K,    // [BH][T][64] bf16
    const ushort_t* __restrict__ Vt,   // [BH][64][T] bf16
    ushort_t* __restrict__ ctx)        // [B][T][C] bf16
{
    __shared__ ushort_t Ps[4][16 * 72];   // per-wave P scratch
    __shared__ float Od[2][1024];         // odd-wave partial O per pair
    __shared__ float Ol[2][16];           // odd-wave partial l per pair

    const int tid  = threadIdx.x;
    const int lane = tid & 63;
    const int wv   = tid >> 6;
    const int m    = lane & 15;
    const int quad = lane >> 4;

    const int pr = blockIdx.x;            // 0 = heaviest pair first
    const int h = blockIdx.y, b = blockIdx.z;
    const int bh = b * NH_ + h;

    const int tw  = (wv < 2) ? (127 - pr) : pr;   // 16-row q-tile index
    const int sp  = wv & 1;                        // key-split parity
    const int t0  = tw * 16;
    const int ext = tw >> 2;                       // last 64-key tile

    const ushort_t* __restrict__ Kg = K  + (size_t)bh * (T_ * HS_);
    const ushort_t* __restrict__ Vg = Vt + (size_t)bh * (HS_ * T_);

    // Q A-frags (held): lane m -> q-row t0+m
    bf16x8 qf0, qf1;
    {
        const ushort_t* qp = Q + ((size_t)bh * T_ + t0 + m) * HS_ + quad * 8;
        qf0 = *(const bf16x8*)(qp);
        qf1 = *(const bf16x8*)(qp + 32);
    }

    floatx4 acc[4];
    #pragma unroll
    for (int dt = 0; dt < 4; ++dt) acc[dt] = (floatx4){0.f, 0.f, 0.f, 0.f};
    float l_lane[4] = {0.f, 0.f, 0.f, 0.f};

    ushort_t* __restrict__ Pw = &Ps[wv][0];

    for (int kt = sp; kt <= ext; kt += 2) {
        const int s0 = kt * 64;

        // ---- S = Q K^T : K B-frags direct from global ----
        floatx4 s[4];
        #pragma unroll
        for (int kg = 0; kg < 4; ++kg) {
            const ushort_t* kp = Kg + (size_t)(s0 + kg * 16 + m) * HS_ + quad * 8;
            bf16x8 k0 = *(const bf16x8*)(kp);
            bf16x8 k1 = *(const bf16x8*)(kp + 32);
            floatx4 a = (floatx4){0.f, 0.f, 0.f, 0.f};
            a = __builtin_amdgcn_mfma_f32_16x16x32_bf16(qf0, k0, a, 0, 0, 0);
            a = __builtin_amdgcn_mfma_f32_16x16x32_bf16(qf1, k1, a, 0, 0, 0);
            s[kg] = a;
        }

        if (kt == ext) {   // diagonal tile: causal mask
            #pragma unroll
            for (int kg = 0; kg < 4; ++kg) {
                const int key = s0 + kg * 16 + m;
                #pragma unroll
                for (int r = 0; r < 4; ++r)
                    if (key > t0 + quad * 4 + r) s[kg][r] = -1e30f;
            }
        }

        // ---- fixed-max softmax; P -> per-wave LDS (transpose to A-layout) ----
        #pragma unroll
        for (int r = 0; r < 4; ++r) {
            const float p0 = __expf(s[0][r]);
            const float p1 = __expf(s[1][r]);
            const float p2 = __expf(s[2][r]);
            const float p3 = __expf(s[3][r]);
            l_lane[r] += (p0 + p1) + (p2 + p3);
            const int pb = (quad * 4 + r) * 72 + m;
            Pw[pb]      = f2bf(p0);
            Pw[pb + 16] = f2bf(p1);
            Pw[pb + 32] = f2bf(p2);
            Pw[pb + 48] = f2bf(p3);
        }
        asm volatile("s_waitcnt lgkmcnt(0)" ::: "memory");
        bf16x8 pf0 = *(const bf16x8*)&Pw[m * 72 + quad * 8];
        bf16x8 pf1 = *(const bf16x8*)&Pw[m * 72 + 32 + quad * 8];

        // ---- O += P V : Vt B-frags direct from global ----
        #pragma unroll
        for (int dt = 0; dt < 4; ++dt) {
            const ushort_t* vp = Vg + (size_t)(dt * 16 + m) * T_ + s0 + quad * 8;
            bf16x8 v0 = *(const bf16x8*)(vp);
            bf16x8 v1 = *(const bf16x8*)(vp + 32);
            acc[dt] = __builtin_amdgcn_mfma_f32_16x16x32_bf16(pf0, v0, acc[dt], 0, 0, 0);
            acc[dt] = __builtin_amdgcn_mfma_f32_16x16x32_bf16(pf1, v1, acc[dt], 0, 0, 0);
        }
    }

    // ---- combine split partials: odd wave dumps, even wave merges ----
    float lr[4];
    #pragma unroll
    for (int r = 0; r < 4; ++r) {
        float ls = l_lane[r];
        ls += __shfl_xor(ls, 1, 64);
        ls += __shfl_xor(ls, 2, 64);
        ls += __shfl_xor(ls, 4, 64);
        ls += __shfl_xor(ls, 8, 64);
        lr[r] = ls;
    }
    const int pairId = wv >> 1;
    if (wv & 1) {
        #pragma unroll
        for (int dt = 0; dt < 4; ++dt)
            *(floatx4*)&Od[pairId][lane * 16 + dt * 4] = acc[dt];
        if (m == 0) {
            #pragma unroll
            for (int r = 0; r < 4; ++r) Ol[pairId][quad * 4 + r] = lr[r];
        }
    }
    __syncthreads();
    if (!(wv & 1)) {
        #pragma unroll
        for (int dt = 0; dt < 4; ++dt) {
            const floatx4 po = *(const floatx4*)&Od[pairId][lane * 16 + dt * 4];
            #pragma unroll
            for (int r = 0; r < 4; ++r) {
                const float lt = lr[r] + Ol[pairId][quad * 4 + r];
                const int t = t0 + quad * 4 + r;
                ctx[((size_t)(b * T_) + t) * C_ + h * HS_ + dt * 16 + m] =
                    f2bf((acc[dt][r] + po[r]) / lt);
            }
        }
    }
}

// ---------------------------------------------------------------------------
// Launcher. ws (ushorts): Wtq|Wtk|Wtv|Wto | Q | K | Vt | ctx  (~26 MB)
// ---------------------------------------------------------------------------
extern "C" void kernel_launch(void* const* d_in, const int* in_sizes, int n_in,
                              void* d_out, int out_size, void* d_ws, size_t ws_size,
                              hipStream_t stream) {
    const float* x  = (const float*)d_in[0];
    const float* Wq = (const float*)d_in[1];
    const float* bq = (const float*)d_in[2];
    const float* Wk = (const float*)d_in[3];
    const float* bk = (const float*)d_in[4];
    const float* Wv = (const float*)d_in[5];
    const float* bv = (const float*)d_in[6];
    const float* Wo = (const float*)d_in[7];
    const float* bo = (const float*)d_in[8];
    float* out = (float*)d_out;

    const size_t per = (size_t)B_ * NH_ * T_ * HS_;  // 3,145,728
    const size_t wsz = 384 * 384;                    // 147,456
    ushort_t* Wtq = (ushort_t*)d_ws;
    ushort_t* Wtk = Wtq + wsz;
    ushort_t* Wtv = Wtk + wsz;
    ushort_t* Wto = Wtv + wsz;
    ushort_t* Qb  = Wto + wsz;
    ushort_t* Kb  = Qb + per;
    ushort_t* Vtb = Kb + per;
    ushort_t* ctxb = Vtb + per;

    prep<<<dim3(144), 256, 0, stream>>>(Wq, Wk, Wv, Wo, Wtq, Wtk, Wtv, Wto);

    qkv_gemm<<<dim3(M_ / 128, 1152 / 128), 256, 0, stream>>>(
        x, Wtq, Wtk, Wtv, bq, bk, bv, Qb, Kb, Vtb);

    attn_mfma<<<dim3(64, NH_, B_), 256, 0, stream>>>(Qb, Kb, Vtb, ctxb);

    proj_gemm<<<dim3(M_ / 128, 384 / 128), 256, 0, stream>>>(ctxb, Wto, bo, out);
}

// Round 6
// 157.809 us; speedup vs baseline: 1.4921x; 1.4921x over previous
//
#include <hip/hip_runtime.h>

#define B_  4
#define T_  2048
#define C_  384
#define NH_ 6
#define HS_ 64
#define M_  (B_*T_)   // 8192 rows

typedef float floatx4 __attribute__((ext_vector_type(4)));
typedef __bf16 bf16x8 __attribute__((ext_vector_type(8)));
typedef unsigned short ushort_t;
typedef unsigned short ushortx8 __attribute__((ext_vector_type(8)));
typedef unsigned short ushortx4 __attribute__((ext_vector_type(4)));

__device__ __forceinline__ ushort_t f2bf(float f) {
    unsigned u = __builtin_bit_cast(unsigned, f);
    unsigned r = (u + 0x7FFFu + ((u >> 16) & 1u)) >> 16;   // RNE
    return (ushort_t)r;
}

// ---------------------------------------------------------------------------
// prep: W transpose-casts (x-cast fused into qkv staging). 144 blocks.
// ---------------------------------------------------------------------------
__global__ __launch_bounds__(256) void prep(
    const float* __restrict__ Wq, const float* __restrict__ Wk,
    const float* __restrict__ Wv, const float* __restrict__ Wo,
    ushort_t* __restrict__ Wtq, ushort_t* __restrict__ Wtk,
    ushort_t* __restrict__ Wtv, ushort_t* __restrict__ Wto)
{
    __shared__ float Ls[64][65];
    const int tid = threadIdx.x;
    const int idx = blockIdx.x;
    const int z = idx / 36, rest = idx % 36;
    const float* __restrict__ W = (z == 0) ? Wq : (z == 1) ? Wk : (z == 2) ? Wv : Wo;
    ushort_t* __restrict__ Wt   = (z == 0) ? Wtq : (z == 1) ? Wtk : (z == 2) ? Wtv : Wto;
    const int k0 = (rest / 6) * 64, n0 = (rest % 6) * 64;

    #pragma unroll
    for (int p = 0; p < 4; ++p) {
        const int kk = p * 16 + (tid >> 4);
        const int nn = (tid & 15) * 4;
        const float4 v = *(const float4*)&W[(size_t)(k0 + kk) * 384 + n0 + nn];
        Ls[kk][nn] = v.x; Ls[kk][nn + 1] = v.y; Ls[kk][nn + 2] = v.z; Ls[kk][nn + 3] = v.w;
    }
    __syncthreads();
    #pragma unroll
    for (int p = 0; p < 4; ++p) {
        const int n = p * 16 + (tid >> 4);
        const int kc = (tid & 15) * 4;
        ushortx4 pk;
        #pragma unroll
        for (int t = 0; t < 4; ++t) pk[t] = f2bf(Ls[kc + t][n]);
        *(ushortx4*)&Wt[(size_t)(n0 + n) * 384 + k0 + kc] = pk;
    }
}

// ---------------------------------------------------------------------------
// Fused QKV MFMA GEMM; x fp32->bf16 on the fly during staging.
// LDS rows = 32 ushorts (4 x 16B chunks); XOR swizzle chunk^((row>>1)&3)
// makes both staging writes and fragment reads conflict-free.
// ---------------------------------------------------------------------------
__global__ __launch_bounds__(256) void qkv_gemm(
    const float* __restrict__ x,
    const ushort_t* __restrict__ Wtq, const ushort_t* __restrict__ Wtk,
    const ushort_t* __restrict__ Wtv,
    const float* __restrict__ bq, const float* __restrict__ bk, const float* __restrict__ bv,
    ushort_t* __restrict__ Qb, ushort_t* __restrict__ Kb, ushort_t* __restrict__ Vtb)
{
    __shared__ ushort_t Sm[2 * 128 * 32];

    const int tid  = threadIdx.x;
    const int lane = tid & 63;
    const int wv   = tid >> 6;
    const int m    = lane & 15;
    const int quad = lane >> 4;

    const int t0 = blockIdx.x * 128;
    const int n0 = blockIdx.y * 128;
    const int which = n0 / 384;
    const int n_in0 = n0 % 384;
    const bool isV = (which == 2);

    const ushort_t* __restrict__ Wt = (which == 0) ? Wtq : (which == 1) ? Wtk : Wtv;

    const int aOff = isV ? 0 : 4096;
    const int bOff = isV ? 4096 : 0;
    const int a0 = (wv & 1) * 64;
    const int b0 = (wv >> 1) * 64;

    floatx4 acc[4][4];
    #pragma unroll
    for (int i = 0; i < 4; ++i)
        #pragma unroll
        for (int j = 0; j < 4; ++j) acc[i][j] = (floatx4){0.f, 0.f, 0.f, 0.f};

    for (int k0 = 0; k0 < 384; k0 += 32) {
        __syncthreads();
        #pragma unroll
        for (int u = 0; u < 2; ++u) {
            const int e = tid + u * 256;
            const int r = e >> 2, c = e & 3;
            const int sw = ((c ^ ((r >> 1) & 3)) << 3);
            const float4 xa = *(const float4*)&x[(size_t)(t0 + r) * 384 + k0 + c * 8];
            const float4 xc = *(const float4*)&x[(size_t)(t0 + r) * 384 + k0 + c * 8 + 4];
            ushortx8 xp;
            xp[0] = f2bf(xa.x); xp[1] = f2bf(xa.y); xp[2] = f2bf(xa.z); xp[3] = f2bf(xa.w);
            xp[4] = f2bf(xc.x); xp[5] = f2bf(xc.y); xp[6] = f2bf(xc.z); xp[7] = f2bf(xc.w);
            *(ushortx8*)&Sm[r * 32 + sw] = xp;
            *(ushortx8*)&Sm[4096 + r * 32 + sw] =
                *(const ushortx8*)&Wt[(size_t)(n_in0 + r) * 384 + k0 + c * 8];
        }
        __syncthreads();

        bf16x8 fA[4], fB[4];
        #pragma unroll
        for (int i = 0; i < 4; ++i) {
            const int ra = a0 + i * 16 + m;
            fA[i] = *(const bf16x8*)&Sm[aOff + ra * 32 + ((quad ^ ((ra >> 1) & 3)) << 3)];
        }
        #pragma unroll
        for (int j = 0; j < 4; ++j) {
            const int rb = b0 + j * 16 + m;
            fB[j] = *(const bf16x8*)&Sm[bOff + rb * 32 + ((quad ^ ((rb >> 1) & 3)) << 3)];
        }
        #pragma unroll
        for (int i = 0; i < 4; ++i)
            #pragma unroll
            for (int j = 0; j < 4; ++j)
                acc[i][j] = __builtin_amdgcn_mfma_f32_16x16x32_bf16(fA[i], fB[j], acc[i][j], 0, 0, 0);
    }

    if (!isV) {
        ushort_t* __restrict__ out = (which == 0) ? Qb : Kb;
        const float* __restrict__ bias = (which == 0) ? bq : bk;
        const float scale = (which == 0) ? 0.125f : 1.0f;
        #pragma unroll
        for (int i = 0; i < 4; ++i) {
            const int n_base = n_in0 + a0 + i * 16 + quad * 4;
            const int h = n_base >> 6, d0 = n_base & 63;
            #pragma unroll
            for (int j = 0; j < 4; ++j) {
                const int tg = t0 + b0 + j * 16 + m;
                const int b = tg >> 11, tb = tg & (T_ - 1);
                ushortx4 pk;
                #pragma unroll
                for (int r = 0; r < 4; ++r)
                    pk[r] = f2bf((acc[i][j][r] + bias[n_base + r]) * scale);
                *(ushortx4*)&out[(((size_t)(b * NH_ + h)) * T_ + tb) * HS_ + d0] = pk;
            }
        }
    } else {
        #pragma unroll
        for (int i = 0; i < 4; ++i) {
            const int tg0 = t0 + a0 + i * 16 + quad * 4;
            const int b = tg0 >> 11, tb0 = tg0 & (T_ - 1);
            #pragma unroll
            for (int j = 0; j < 4; ++j) {
                const int n_l = n_in0 + b0 + j * 16 + m;
                const int h = n_l >> 6, d = n_l & 63;
                const float bb = bv[n_l];
                ushortx4 pk;
                #pragma unroll
                for (int r = 0; r < 4; ++r) pk[r] = f2bf(acc[i][j][r] + bb);
                *(ushortx4*)&Vtb[(((size_t)(b * NH_ + h)) * HS_ + d) * T_ + tb0] = pk;
            }
        }
    }
}

// ---------------------------------------------------------------------------
// Output projection MFMA GEMM, same swizzle fix.
// ---------------------------------------------------------------------------
__global__ __launch_bounds__(256) void proj_gemm(
    const ushort_t* __restrict__ ctxb,
    const ushort_t* __restrict__ Wto,
    const float* __restrict__ bo,
    float* __restrict__ out)
{
    __shared__ ushort_t Sm[2 * 128 * 32];

    const int tid  = threadIdx.x;
    const int lane = tid & 63;
    const int wv   = tid >> 6;
    const int m    = lane & 15;
    const int quad = lane >> 4;

    const int t0 = blockIdx.x * 128;
    const int n0 = blockIdx.y * 128;
    const int a0 = (wv & 1) * 64;
    const int b0 = (wv >> 1) * 64;

    floatx4 acc[4][4];
    #pragma unroll
    for (int i = 0; i < 4; ++i)
        #pragma unroll
        for (int j = 0; j < 4; ++j) acc[i][j] = (floatx4){0.f, 0.f, 0.f, 0.f};

    for (int k0 = 0; k0 < 384; k0 += 32) {
        __syncthreads();
        #pragma unroll
        for (int u = 0; u < 2; ++u) {
            const int e = tid + u * 256;
            const int r = e >> 2, c = e & 3;
            const int sw = ((c ^ ((r >> 1) & 3)) << 3);
            *(ushortx8*)&Sm[r * 32 + sw] =
                *(const ushortx8*)&ctxb[(size_t)(t0 + r) * 384 + k0 + c * 8];
            *(ushortx8*)&Sm[4096 + r * 32 + sw] =
                *(const ushortx8*)&Wto[(size_t)(n0 + r) * 384 + k0 + c * 8];
        }
        __syncthreads();

        bf16x8 fA[4], fB[4];
        #pragma unroll
        for (int i = 0; i < 4; ++i) {
            const int ra = a0 + i * 16 + m;
            fA[i] = *(const bf16x8*)&Sm[4096 + ra * 32 + ((quad ^ ((ra >> 1) & 3)) << 3)];
        }
        #pragma unroll
        for (int j = 0; j < 4; ++j) {
            const int rb = b0 + j * 16 + m;
            fB[j] = *(const bf16x8*)&Sm[rb * 32 + ((quad ^ ((rb >> 1) & 3)) << 3)];
        }
        #pragma unroll
        for (int i = 0; i < 4; ++i)
            #pragma unroll
            for (int j = 0; j < 4; ++j)
                acc[i][j] = __builtin_amdgcn_mfma_f32_16x16x32_bf16(fA[i], fB[j], acc[i][j], 0, 0, 0);
    }

    #pragma unroll
    for (int i = 0; i < 4; ++i) {
        const int n_base = n0 + a0 + i * 16 + quad * 4;
        const float4 bb = *(const float4*)&bo[n_base];
        #pragma unroll
        for (int j = 0; j < 4; ++j) {
            const int tg = t0 + b0 + j * 16 + m;
            float4 o;
            o.x = acc[i][j][0] + bb.x;
            o.y = acc[i][j][1] + bb.y;
            o.z = acc[i][j][2] + bb.z;
            o.w = acc[i][j][3] + bb.w;
            *(float4*)&out[(size_t)tg * 384 + n_base] = o;
        }
    }
}

// ---------------------------------------------------------------------------
// MFMA flash attention: R4 structure (pair-balanced, swizzled LDS, fixed-max
// softmax) + double-buffered K/V staging with ONE barrier per k-tile.
// Per iter: ds_write regs->buf[kt&1]; prefetch tile kt+1 global->regs;
// __syncthreads; compute on buf[kt&1]. Gen-(kt+1) writes vs gen-(kt-1) reads
// of the same buffer are separated by barrier(kt); within-wave DS pipe is
// in-order, so one barrier is sufficient.
// ---------------------------------------------------------------------------
__global__ __launch_bounds__(256) void attn_mfma(
    const ushort_t* __restrict__ Q,    // [BH][T][64] bf16, pre-scaled 1/8
    const ushort_t* __restrict__ K,    // [BH][T][64] bf16
    const ushort_t* __restrict__ Vt,   // [BH][64][T] bf16
    ushort_t* __restrict__ ctx)        // [B][T][C] bf16
{
    __shared__ ushort_t Ks[2][64 * 64];
    __shared__ ushort_t Vs[2][64 * 64];
    __shared__ ushort_t Ps[4][16 * 64];

    const int tid  = threadIdx.x;
    const int lane = tid & 63;
    const int wv   = tid >> 6;
    const int m    = lane & 15;
    const int quad = lane >> 4;
    const int cA   = (quad ^ (m & 7)) << 3;      // swizzled chunk, lo 32 of k/d

    const int p = blockIdx.x;
    const int h = blockIdx.y, b = blockIdx.z;
    const int bh = b * NH_ + h;

    const int tileHi = 63 - p;
    const int rowbase = ((wv < 2) ? tileHi : p) * 32 + (wv & 1) * 16;
    const int myext = rowbase >> 6;
    const int blockext = tileHi >> 1;

    const ushort_t* __restrict__ Kg = K  + (size_t)bh * (T_ * HS_);
    const ushort_t* __restrict__ Vg = Vt + (size_t)bh * (HS_ * T_);

    // fixed per-thread staging coordinates (two elements per thread)
    const int r0 = tid >> 3,        c0 = tid & 7;
    const int r1 = (tid + 256) >> 3, c1 = tid & 7;   // (tid+256)&7 == tid&7
    const int sw0 = ((c0 ^ (r0 & 7)) << 3);
    const int sw1 = ((c1 ^ (r1 & 7)) << 3);

    // Q A-frags
    bf16x8 qf0, qf1;
    {
        const ushort_t* qp = Q + ((size_t)bh * T_ + rowbase + m) * HS_;
        qf0 = *(const bf16x8*)(qp + quad * 8);
        qf1 = *(const bf16x8*)(qp + 32 + quad * 8);
    }

    floatx4 acc_o[4];
    #pragma unroll
    for (int dt = 0; dt < 4; ++dt) acc_o[dt] = (floatx4){0.f, 0.f, 0.f, 0.f};
    float l_lane[4] = {0.f, 0.f, 0.f, 0.f};

    ushort_t* __restrict__ Pw = &Ps[wv][0];

    // prologue: tile 0 -> regs
    ushortx8 kr0 = *(const ushortx8*)&Kg[(size_t)r0 * HS_ + c0 * 8];
    ushortx8 kr1 = *(const ushortx8*)&Kg[(size_t)r1 * HS_ + c1 * 8];
    ushortx8 vr0 = *(const ushortx8*)&Vg[(size_t)r0 * T_ + c0 * 8];
    ushortx8 vr1 = *(const ushortx8*)&Vg[(size_t)r1 * T_ + c1 * 8];

    for (int kt = 0; kt <= blockext; ++kt) {
        ushort_t* __restrict__ Kc = &Ks[kt & 1][0];
        ushort_t* __restrict__ Vc = &Vs[kt & 1][0];
        *(ushortx8*)&Kc[r0 * 64 + sw0] = kr0;
        *(ushortx8*)&Kc[r1 * 64 + sw1] = kr1;
        *(ushortx8*)&Vc[r0 * 64 + sw0] = vr0;
        *(ushortx8*)&Vc[r1 * 64 + sw1] = vr1;

        if (kt < blockext) {   // prefetch next tile into regs (in flight across barrier)
            const int s1 = (kt + 1) * 64;
            kr0 = *(const ushortx8*)&Kg[(size_t)(s1 + r0) * HS_ + c0 * 8];
            kr1 = *(const ushortx8*)&Kg[(size_t)(s1 + r1) * HS_ + c1 * 8];
            vr0 = *(const ushortx8*)&Vg[(size_t)r0 * T_ + s1 + c0 * 8];
            vr1 = *(const ushortx8*)&Vg[(size_t)r1 * T_ + s1 + c1 * 8];
        }
        __syncthreads();

        if (kt > myext) continue;

        // ---- S = Q K^T ----
        floatx4 s[4];
        #pragma unroll
        for (int kc = 0; kc < 4; ++kc) {
            const int kb = (kc * 16 + m) * 64;
            bf16x8 k0 = *(const bf16x8*)&Kc[kb + cA];
            bf16x8 k1 = *(const bf16x8*)&Kc[kb + (cA ^ 32)];
            floatx4 a = (floatx4){0.f, 0.f, 0.f, 0.f};
            a = __builtin_amdgcn_mfma_f32_16x16x32_bf16(qf0, k0, a, 0, 0, 0);
            a = __builtin_amdgcn_mfma_f32_16x16x32_bf16(qf1, k1, a, 0, 0, 0);
            s[kc] = a;
        }

        if (kt == myext) {   // diagonal: causal mask
            #pragma unroll
            for (int kc = 0; kc < 4; ++kc) {
                const int key = kt * 64 + kc * 16 + m;
                #pragma unroll
                for (int r = 0; r < 4; ++r)
                    if (key > rowbase + quad * 4 + r) s[kc][r] = -1e30f;
            }
        }

        // ---- fixed-max softmax; P -> per-wave swizzled LDS ----
        const int mc = m >> 3, mp = m & 7;
        #pragma unroll
        for (int r = 0; r < 4; ++r) {
            const int prow = quad * 4 + r;
            const int psw = prow & 7;
            const float p0 = __expf(s[0][r]);
            const float p1 = __expf(s[1][r]);
            const float p2 = __expf(s[2][r]);
            const float p3 = __expf(s[3][r]);
            l_lane[r] += (p0 + p1) + (p2 + p3);
            const int pb = prow * 64 + mp;
            Pw[pb + (((0 + mc) ^ psw) << 3)] = f2bf(p0);
            Pw[pb + (((2 + mc) ^ psw) << 3)] = f2bf(p1);
            Pw[pb + (((4 + mc) ^ psw) << 3)] = f2bf(p2);
            Pw[pb + (((6 + mc) ^ psw) << 3)] = f2bf(p3);
        }
        asm volatile("s_waitcnt lgkmcnt(0)" ::: "memory");
        bf16x8 pf0 = *(const bf16x8*)&Pw[m * 64 + cA];
        bf16x8 pf1 = *(const bf16x8*)&Pw[m * 64 + (cA ^ 32)];

        // ---- O += P V ----
        #pragma unroll
        for (int dt = 0; dt < 4; ++dt) {
            const int vb = (dt * 16 + m) * 64;
            bf16x8 v0 = *(const bf16x8*)&Vc[vb + cA];
            bf16x8 v1 = *(const bf16x8*)&Vc[vb + (cA ^ 32)];
            acc_o[dt] = __builtin_amdgcn_mfma_f32_16x16x32_bf16(pf0, v0, acc_o[dt], 0, 0, 0);
            acc_o[dt] = __builtin_amdgcn_mfma_f32_16x16x32_bf16(pf1, v1, acc_o[dt], 0, 0, 0);
        }
    }

    // epilogue
    float l[4];
    #pragma unroll
    for (int r = 0; r < 4; ++r) {
        float ls = l_lane[r];
        ls += __shfl_xor(ls, 1, 64);
        ls += __shfl_xor(ls, 2, 64);
        ls += __shfl_xor(ls, 4, 64);
        ls += __shfl_xor(ls, 8, 64);
        l[r] = ls;
    }
    #pragma unroll
    for (int dt = 0; dt < 4; ++dt) {
        #pragma unroll
        for (int r = 0; r < 4; ++r) {
            const int t = rowbase + quad * 4 + r;
            ctx[((size_t)(b * T_) + t) * C_ + h * HS_ + dt * 16 + m] =
                f2bf(acc_o[dt][r] / l[r]);
        }
    }
}

// ---------------------------------------------------------------------------
// Launcher. ws (ushorts): Wtq|Wtk|Wtv|Wto | Q | K | Vt | ctx  (~26 MB)
// ---------------------------------------------------------------------------
extern "C" void kernel_launch(void* const* d_in, const int* in_sizes, int n_in,
                              void* d_out, int out_size, void* d_ws, size_t ws_size,
                              hipStream_t stream) {
    const float* x  = (const float*)d_in[0];
    const float* Wq = (const float*)d_in[1];
    const float* bq = (const float*)d_in[2];
    const float* Wk = (const float*)d_in[3];
    const float* bk = (const float*)d_in[4];
    const float* Wv = (const float*)d_in[5];
    const float* bv = (const float*)d_in[6];
    const float* Wo = (const float*)d_in[7];
    const float* bo = (const float*)d_in[8];
    float* out = (float*)d_out;

    const size_t per = (size_t)B_ * NH_ * T_ * HS_;  // 3,145,728
    const size_t wsz = 384 * 384;                    // 147,456
    ushort_t* Wtq = (ushort_t*)d_ws;
    ushort_t* Wtk = Wtq + wsz;
    ushort_t* Wtv = Wtk + wsz;
    ushort_t* Wto = Wtv + wsz;
    ushort_t* Qb  = Wto + wsz;
    ushort_t* Kb  = Qb + per;
    ushort_t* Vtb = Kb + per;
    ushort_t* ctxb = Vtb + per;

    prep<<<dim3(144), 256, 0, stream>>>(Wq, Wk, Wv, Wo, Wtq, Wtk, Wtv, Wto);

    qkv_gemm<<<dim3(M_ / 128, 1152 / 128), 256, 0, stream>>>(
        x, Wtq, Wtk, Wtv, bq, bk, bv, Qb, Kb, Vtb);

    attn_mfma<<<dim3(32, NH_, B_), 256, 0, stream>>>(Qb, Kb, Vtb, ctxb);

    proj_gemm<<<dim3(M_ / 128, 384 / 128), 256, 0, stream>>>(ctxb, Wto, bo, out);
}

// Round 7
// 150.461 us; speedup vs baseline: 1.5650x; 1.0488x over previous
//
#include <hip/hip_runtime.h>

#define B_  4
#define T_  2048
#define C_  384
#define NH_ 6
#define HS_ 64
#define M_  (B_*T_)   // 8192 rows

typedef float floatx4 __attribute__((ext_vector_type(4)));
typedef __bf16 bf16x8 __attribute__((ext_vector_type(8)));
typedef unsigned short ushort_t;
typedef unsigned short ushortx8 __attribute__((ext_vector_type(8)));
typedef unsigned short ushortx4 __attribute__((ext_vector_type(4)));

__device__ __forceinline__ ushort_t f2bf(float f) {
    unsigned u = __builtin_bit_cast(unsigned, f);
    unsigned r = (u + 0x7FFFu + ((u >> 16) & 1u)) >> 16;   // RNE
    return (ushort_t)r;
}

// ---------------------------------------------------------------------------
// prep: x fp32->bf16 cast (blocks [0,1536)) + W transpose-casts ([1536,1680)).
// ---------------------------------------------------------------------------
__global__ __launch_bounds__(256) void prep(
    const float* __restrict__ x, ushort_t* __restrict__ xb,
    const float* __restrict__ Wq, const float* __restrict__ Wk,
    const float* __restrict__ Wv, const float* __restrict__ Wo,
    ushort_t* __restrict__ Wtq, ushort_t* __restrict__ Wtk,
    ushort_t* __restrict__ Wtv, ushort_t* __restrict__ Wto)
{
    __shared__ float Ls[64][65];
    const int tid = threadIdx.x;
    const int bx = blockIdx.x;

    if (bx < 1536) {
        const int i = (bx * 256 + tid) * 8;
        const float4 a = *(const float4*)&x[i];
        const float4 b = *(const float4*)&x[i + 4];
        ushortx8 p;
        p[0] = f2bf(a.x); p[1] = f2bf(a.y); p[2] = f2bf(a.z); p[3] = f2bf(a.w);
        p[4] = f2bf(b.x); p[5] = f2bf(b.y); p[6] = f2bf(b.z); p[7] = f2bf(b.w);
        *(ushortx8*)&xb[i] = p;
        return;
    }

    const int idx = bx - 1536;
    const int z = idx / 36, rest = idx % 36;
    const float* __restrict__ W = (z == 0) ? Wq : (z == 1) ? Wk : (z == 2) ? Wv : Wo;
    ushort_t* __restrict__ Wt   = (z == 0) ? Wtq : (z == 1) ? Wtk : (z == 2) ? Wtv : Wto;
    const int k0 = (rest / 6) * 64, n0 = (rest % 6) * 64;

    #pragma unroll
    for (int p = 0; p < 4; ++p) {
        const int kk = p * 16 + (tid >> 4);
        const int nn = (tid & 15) * 4;
        const float4 v = *(const float4*)&W[(size_t)(k0 + kk) * 384 + n0 + nn];
        Ls[kk][nn] = v.x; Ls[kk][nn + 1] = v.y; Ls[kk][nn + 2] = v.z; Ls[kk][nn + 3] = v.w;
    }
    __syncthreads();
    #pragma unroll
    for (int p = 0; p < 4; ++p) {
        const int n = p * 16 + (tid >> 4);
        const int kc = (tid & 15) * 4;
        ushortx4 pk;
        #pragma unroll
        for (int t = 0; t < 4; ++t) pk[t] = f2bf(Ls[kc + t][n]);
        *(ushortx4*)&Wt[(size_t)(n0 + n) * 384 + k0 + kc] = pk;
    }
}

// ---------------------------------------------------------------------------
// Fused QKV MFMA GEMM, single-barrier software pipeline:
//   ds_write(regs) -> barrier (cheap: vmcnt==0) -> prefetch next k-slab ->
//   compute. Double-buffered LDS; XOR-swizzled rows (conflict-free).
// ---------------------------------------------------------------------------
__global__ __launch_bounds__(256) void qkv_gemm(
    const ushort_t* __restrict__ xb,
    const ushort_t* __restrict__ Wtq, const ushort_t* __restrict__ Wtk,
    const ushort_t* __restrict__ Wtv,
    const float* __restrict__ bq, const float* __restrict__ bk, const float* __restrict__ bv,
    ushort_t* __restrict__ Qb, ushort_t* __restrict__ Kb, ushort_t* __restrict__ Vtb)
{
    __shared__ ushort_t Sm[2][8192];   // [buf][ x-tile 4096 | W-tile 4096 ]

    const int tid  = threadIdx.x;
    const int lane = tid & 63;
    const int wv   = tid >> 6;
    const int m    = lane & 15;
    const int quad = lane >> 4;

    const int t0 = blockIdx.x * 128;
    const int n0 = blockIdx.y * 128;
    const int which = n0 / 384;
    const int n_in0 = n0 % 384;
    const bool isV = (which == 2);

    const ushort_t* __restrict__ Wt = (which == 0) ? Wtq : (which == 1) ? Wtk : Wtv;

    const int aOff = isV ? 0 : 4096;
    const int bOff = isV ? 4096 : 0;
    const int a0 = (wv & 1) * 64;
    const int b0 = (wv >> 1) * 64;

    // staging coords: 2 chunks per thread per tile
    const int rs0 = tid >> 2,         cs0 = tid & 3;
    const int rs1 = (tid + 256) >> 2, cs1 = tid & 3;
    const int sw0 = ((cs0 ^ ((rs0 >> 1) & 3)) << 3);
    const int sw1 = ((cs1 ^ ((rs1 >> 1) & 3)) << 3);

    floatx4 acc[4][4];
    #pragma unroll
    for (int i = 0; i < 4; ++i)
        #pragma unroll
        for (int j = 0; j < 4; ++j) acc[i][j] = (floatx4){0.f, 0.f, 0.f, 0.f};

    // prologue: k-slab 0 -> regs
    ushortx8 xr0 = *(const ushortx8*)&xb[(size_t)(t0 + rs0) * 384 + cs0 * 8];
    ushortx8 xr1 = *(const ushortx8*)&xb[(size_t)(t0 + rs1) * 384 + cs1 * 8];
    ushortx8 wr0 = *(const ushortx8*)&Wt[(size_t)(n_in0 + rs0) * 384 + cs0 * 8];
    ushortx8 wr1 = *(const ushortx8*)&Wt[(size_t)(n_in0 + rs1) * 384 + cs1 * 8];

    for (int ks = 0; ks < 12; ++ks) {
        ushort_t* __restrict__ S = &Sm[ks & 1][0];
        *(ushortx8*)&S[rs0 * 32 + sw0] = xr0;
        *(ushortx8*)&S[rs1 * 32 + sw1] = xr1;
        *(ushortx8*)&S[4096 + rs0 * 32 + sw0] = wr0;
        *(ushortx8*)&S[4096 + rs1 * 32 + sw1] = wr1;
        __syncthreads();

        if (ks < 11) {   // prefetch AFTER barrier: latency hides under compute
            const int kk = (ks + 1) * 32;
            xr0 = *(const ushortx8*)&xb[(size_t)(t0 + rs0) * 384 + kk + cs0 * 8];
            xr1 = *(const ushortx8*)&xb[(size_t)(t0 + rs1) * 384 + kk + cs1 * 8];
            wr0 = *(const ushortx8*)&Wt[(size_t)(n_in0 + rs0) * 384 + kk + cs0 * 8];
            wr1 = *(const ushortx8*)&Wt[(size_t)(n_in0 + rs1) * 384 + kk + cs1 * 8];
        }

        bf16x8 fA[4], fB[4];
        #pragma unroll
        for (int i = 0; i < 4; ++i) {
            const int ra = a0 + i * 16 + m;
            fA[i] = *(const bf16x8*)&S[aOff + ra * 32 + ((quad ^ ((ra >> 1) & 3)) << 3)];
        }
        #pragma unroll
        for (int j = 0; j < 4; ++j) {
            const int rb = b0 + j * 16 + m;
            fB[j] = *(const bf16x8*)&S[bOff + rb * 32 + ((quad ^ ((rb >> 1) & 3)) << 3)];
        }
        #pragma unroll
        for (int i = 0; i < 4; ++i)
            #pragma unroll
            for (int j = 0; j < 4; ++j)
                acc[i][j] = __builtin_amdgcn_mfma_f32_16x16x32_bf16(fA[i], fB[j], acc[i][j], 0, 0, 0);
    }

    if (!isV) {
        ushort_t* __restrict__ out = (which == 0) ? Qb : Kb;
        const float* __restrict__ bias = (which == 0) ? bq : bk;
        const float scale = (which == 0) ? 0.125f : 1.0f;
        #pragma unroll
        for (int i = 0; i < 4; ++i) {
            const int n_base = n_in0 + a0 + i * 16 + quad * 4;
            const int h = n_base >> 6, d0 = n_base & 63;
            #pragma unroll
            for (int j = 0; j < 4; ++j) {
                const int tg = t0 + b0 + j * 16 + m;
                const int b = tg >> 11, tb = tg & (T_ - 1);
                ushortx4 pk;
                #pragma unroll
                for (int r = 0; r < 4; ++r)
                    pk[r] = f2bf((acc[i][j][r] + bias[n_base + r]) * scale);
                *(ushortx4*)&out[(((size_t)(b * NH_ + h)) * T_ + tb) * HS_ + d0] = pk;
            }
        }
    } else {
        #pragma unroll
        for (int i = 0; i < 4; ++i) {
            const int tg0 = t0 + a0 + i * 16 + quad * 4;
            const int b = tg0 >> 11, tb0 = tg0 & (T_ - 1);
            #pragma unroll
            for (int j = 0; j < 4; ++j) {
                const int n_l = n_in0 + b0 + j * 16 + m;
                const int h = n_l >> 6, d = n_l & 63;
                const float bb = bv[n_l];
                ushortx4 pk;
                #pragma unroll
                for (int r = 0; r < 4; ++r) pk[r] = f2bf(acc[i][j][r] + bb);
                *(ushortx4*)&Vtb[(((size_t)(b * NH_ + h)) * HS_ + d) * T_ + tb0] = pk;
            }
        }
    }
}

// ---------------------------------------------------------------------------
// Output projection: BM=64 x BN=128 tiles (384 blocks), same pipeline.
// Wave: 64 n-rows (A from Wto) x 32 t-rows (B from ctx): acc[4][2].
// ---------------------------------------------------------------------------
__global__ __launch_bounds__(256) void proj_gemm(
    const ushort_t* __restrict__ ctxb,
    const ushort_t* __restrict__ Wto,
    const float* __restrict__ bo,
    float* __restrict__ out)
{
    __shared__ ushort_t Sm[2][6144];   // [buf][ ctx 64x32 = 2048 | W 128x32 = 4096 ]

    const int tid  = threadIdx.x;
    const int lane = tid & 63;
    const int wv   = tid >> 6;
    const int m    = lane & 15;
    const int quad = lane >> 4;

    const int t0 = blockIdx.x * 64;
    const int n0 = blockIdx.y * 128;
    const int a0 = (wv & 1) * 64;      // n offset within 128
    const int b0 = (wv >> 1) * 32;     // t offset within 64

    // staging: ctx 1 chunk/thread; W 2 chunks/thread
    const int rc = tid >> 2,          cc = tid & 3;           // ctx: 64 rows
    const int rw0 = tid >> 2,         cw0 = tid & 3;          // W rows 0..63
    const int rw1 = (tid + 256) >> 2, cw1 = tid & 3;          // W rows 64..127
    const int swc  = ((cc  ^ ((rc  >> 1) & 3)) << 3);
    const int sww0 = ((cw0 ^ ((rw0 >> 1) & 3)) << 3);
    const int sww1 = ((cw1 ^ ((rw1 >> 1) & 3)) << 3);

    floatx4 acc[4][2];
    #pragma unroll
    for (int i = 0; i < 4; ++i)
        #pragma unroll
        for (int j = 0; j < 2; ++j) acc[i][j] = (floatx4){0.f, 0.f, 0.f, 0.f};

    ushortx8 cr  = *(const ushortx8*)&ctxb[(size_t)(t0 + rc) * 384 + cc * 8];
    ushortx8 wr0 = *(const ushortx8*)&Wto[(size_t)(n0 + rw0) * 384 + cw0 * 8];
    ushortx8 wr1 = *(const ushortx8*)&Wto[(size_t)(n0 + rw1) * 384 + cw1 * 8];

    for (int ks = 0; ks < 12; ++ks) {
        ushort_t* __restrict__ S = &Sm[ks & 1][0];
        *(ushortx8*)&S[rc * 32 + swc] = cr;
        *(ushortx8*)&S[2048 + rw0 * 32 + sww0] = wr0;
        *(ushortx8*)&S[2048 + rw1 * 32 + sww1] = wr1;
        __syncthreads();

        if (ks < 11) {
            const int kk = (ks + 1) * 32;
            cr  = *(const ushortx8*)&ctxb[(size_t)(t0 + rc) * 384 + kk + cc * 8];
            wr0 = *(const ushortx8*)&Wto[(size_t)(n0 + rw0) * 384 + kk + cw0 * 8];
            wr1 = *(const ushortx8*)&Wto[(size_t)(n0 + rw1) * 384 + kk + cw1 * 8];
        }

        bf16x8 fA[4], fB[2];
        #pragma unroll
        for (int i = 0; i < 4; ++i) {
            const int ra = a0 + i * 16 + m;
            fA[i] = *(const bf16x8*)&S[2048 + ra * 32 + ((quad ^ ((ra >> 1) & 3)) << 3)];
        }
        #pragma unroll
        for (int j = 0; j < 2; ++j) {
            const int rb = b0 + j * 16 + m;
            fB[j] = *(const bf16x8*)&S[rb * 32 + ((quad ^ ((rb >> 1) & 3)) << 3)];
        }
        #pragma unroll
        for (int i = 0; i < 4; ++i)
            #pragma unroll
            for (int j = 0; j < 2; ++j)
                acc[i][j] = __builtin_amdgcn_mfma_f32_16x16x32_bf16(fA[i], fB[j], acc[i][j], 0, 0, 0);
    }

    #pragma unroll
    for (int i = 0; i < 4; ++i) {
        const int n_base = n0 + a0 + i * 16 + quad * 4;
        const float4 bb = *(const float4*)&bo[n_base];
        #pragma unroll
        for (int j = 0; j < 2; ++j) {
            const int tg = t0 + b0 + j * 16 + m;
            float4 o;
            o.x = acc[i][j][0] + bb.x;
            o.y = acc[i][j][1] + bb.y;
            o.z = acc[i][j][2] + bb.z;
            o.w = acc[i][j][3] + bb.w;
            *(float4*)&out[(size_t)tg * 384 + n_base] = o;
        }
    }
}

// ---------------------------------------------------------------------------
// MFMA flash attention: pair-balanced, swizzled, double-buffered, ONE cheap
// barrier per k-tile. Order: ds_write(regs) -> barrier (vmcnt already 0) ->
// prefetch kt+1 (latency hides under compute) -> compute.
// ---------------------------------------------------------------------------
__global__ __launch_bounds__(256) void attn_mfma(
    const ushort_t* __restrict__ Q,    // [BH][T][64] bf16, pre-scaled 1/8
    const ushort_t* __restrict__ K,    // [BH][T][64] bf16
    const ushort_t* __restrict__ Vt,   // [BH][64][T] bf16
    ushort_t* __restrict__ ctx)        // [B][T][C] bf16
{
    __shared__ ushort_t Ks[2][64 * 64];
    __shared__ ushort_t Vs[2][64 * 64];
    __shared__ ushort_t Ps[4][16 * 64];

    const int tid  = threadIdx.x;
    const int lane = tid & 63;
    const int wv   = tid >> 6;
    const int m    = lane & 15;
    const int quad = lane >> 4;
    const int cA   = (quad ^ (m & 7)) << 3;

    const int p = blockIdx.x;
    const int h = blockIdx.y, b = blockIdx.z;
    const int bh = b * NH_ + h;

    const int tileHi = 63 - p;
    const int rowbase = ((wv < 2) ? tileHi : p) * 32 + (wv & 1) * 16;
    const int myext = rowbase >> 6;
    const int blockext = tileHi >> 1;

    const ushort_t* __restrict__ Kg = K  + (size_t)bh * (T_ * HS_);
    const ushort_t* __restrict__ Vg = Vt + (size_t)bh * (HS_ * T_);

    const int r0 = tid >> 3,         c0 = tid & 7;
    const int r1 = (tid + 256) >> 3, c1 = tid & 7;
    const int sw0 = ((c0 ^ (r0 & 7)) << 3);
    const int sw1 = ((c1 ^ (r1 & 7)) << 3);

    bf16x8 qf0, qf1;
    {
        const ushort_t* qp = Q + ((size_t)bh * T_ + rowbase + m) * HS_;
        qf0 = *(const bf16x8*)(qp + quad * 8);
        qf1 = *(const bf16x8*)(qp + 32 + quad * 8);
    }

    floatx4 acc_o[4];
    #pragma unroll
    for (int dt = 0; dt < 4; ++dt) acc_o[dt] = (floatx4){0.f, 0.f, 0.f, 0.f};
    float l_lane[4] = {0.f, 0.f, 0.f, 0.f};

    ushort_t* __restrict__ Pw = &Ps[wv][0];

    // prologue: tile 0 -> regs
    ushortx8 kr0 = *(const ushortx8*)&Kg[(size_t)r0 * HS_ + c0 * 8];
    ushortx8 kr1 = *(const ushortx8*)&Kg[(size_t)r1 * HS_ + c1 * 8];
    ushortx8 vr0 = *(const ushortx8*)&Vg[(size_t)r0 * T_ + c0 * 8];
    ushortx8 vr1 = *(const ushortx8*)&Vg[(size_t)r1 * T_ + c1 * 8];

    for (int kt = 0; kt <= blockext; ++kt) {
        ushort_t* __restrict__ Kc = &Ks[kt & 1][0];
        ushort_t* __restrict__ Vc = &Vs[kt & 1][0];
        *(ushortx8*)&Kc[r0 * 64 + sw0] = kr0;
        *(ushortx8*)&Kc[r1 * 64 + sw1] = kr1;
        *(ushortx8*)&Vc[r0 * 64 + sw0] = vr0;
        *(ushortx8*)&Vc[r1 * 64 + sw1] = vr1;
        __syncthreads();   // vmcnt already drained by the ds_writes; cheap

        if (kt < blockext) {   // prefetch AFTER barrier -> hides under compute
            const int s1 = (kt + 1) * 64;
            kr0 = *(const ushortx8*)&Kg[(size_t)(s1 + r0) * HS_ + c0 * 8];
            kr1 = *(const ushortx8*)&Kg[(size_t)(s1 + r1) * HS_ + c1 * 8];
            vr0 = *(const ushortx8*)&Vg[(size_t)r0 * T_ + s1 + c0 * 8];
            vr1 = *(const ushortx8*)&Vg[(size_t)r1 * T_ + s1 + c1 * 8];
        }

        if (kt > myext) continue;

        // ---- S = Q K^T ----
        floatx4 s[4];
        #pragma unroll
        for (int kc = 0; kc < 4; ++kc) {
            const int kb = (kc * 16 + m) * 64;
            bf16x8 k0 = *(const bf16x8*)&Kc[kb + cA];
            bf16x8 k1 = *(const bf16x8*)&Kc[kb + (cA ^ 32)];
            floatx4 a = (floatx4){0.f, 0.f, 0.f, 0.f};
            a = __builtin_amdgcn_mfma_f32_16x16x32_bf16(qf0, k0, a, 0, 0, 0);
            a = __builtin_amdgcn_mfma_f32_16x16x32_bf16(qf1, k1, a, 0, 0, 0);
            s[kc] = a;
        }

        if (kt == myext) {   // diagonal: causal mask
            #pragma unroll
            for (int kc = 0; kc < 4; ++kc) {
                const int key = kt * 64 + kc * 16 + m;
                #pragma unroll
                for (int r = 0; r < 4; ++r)
                    if (key > rowbase + quad * 4 + r) s[kc][r] = -1e30f;
            }
        }

        // ---- fixed-max softmax; P -> per-wave swizzled LDS ----
        const int mc = m >> 3, mp = m & 7;
        #pragma unroll
        for (int r = 0; r < 4; ++r) {
            const int prow = quad * 4 + r;
            const int psw = prow & 7;
            const float p0 = __expf(s[0][r]);
            const float p1 = __expf(s[1][r]);
            const float p2 = __expf(s[2][r]);
            const float p3 = __expf(s[3][r]);
            l_lane[r] += (p0 + p1) + (p2 + p3);
            const int pb = prow * 64 + mp;
            Pw[pb + (((0 + mc) ^ psw) << 3)] = f2bf(p0);
            Pw[pb + (((2 + mc) ^ psw) << 3)] = f2bf(p1);
            Pw[pb + (((4 + mc) ^ psw) << 3)] = f2bf(p2);
            Pw[pb + (((6 + mc) ^ psw) << 3)] = f2bf(p3);
        }
        asm volatile("s_waitcnt lgkmcnt(0)" ::: "memory");
        bf16x8 pf0 = *(const bf16x8*)&Pw[m * 64 + cA];
        bf16x8 pf1 = *(const bf16x8*)&Pw[m * 64 + (cA ^ 32)];

        // ---- O += P V ----
        #pragma unroll
        for (int dt = 0; dt < 4; ++dt) {
            const int vb = (dt * 16 + m) * 64;
            bf16x8 v0 = *(const bf16x8*)&Vc[vb + cA];
            bf16x8 v1 = *(const bf16x8*)&Vc[vb + (cA ^ 32)];
            acc_o[dt] = __builtin_amdgcn_mfma_f32_16x16x32_bf16(pf0, v0, acc_o[dt], 0, 0, 0);
            acc_o[dt] = __builtin_amdgcn_mfma_f32_16x16x32_bf16(pf1, v1, acc_o[dt], 0, 0, 0);
        }
    }

    // epilogue
    float l[4];
    #pragma unroll
    for (int r = 0; r < 4; ++r) {
        float ls = l_lane[r];
        ls += __shfl_xor(ls, 1, 64);
        ls += __shfl_xor(ls, 2, 64);
        ls += __shfl_xor(ls, 4, 64);
        ls += __shfl_xor(ls, 8, 64);
        l[r] = ls;
    }
    #pragma unroll
    for (int dt = 0; dt < 4; ++dt) {
        #pragma unroll
        for (int r = 0; r < 4; ++r) {
            const int t = rowbase + quad * 4 + r;
            ctx[((size_t)(b * T_) + t) * C_ + h * HS_ + dt * 16 + m] =
                f2bf(acc_o[dt][r] / l[r]);
        }
    }
}

// ---------------------------------------------------------------------------
// Launcher. ws (ushorts): xb | Wtq|Wtk|Wtv|Wto | Q | K | Vt | ctx  (~32 MB)
// ---------------------------------------------------------------------------
extern "C" void kernel_launch(void* const* d_in, const int* in_sizes, int n_in,
                              void* d_out, int out_size, void* d_ws, size_t ws_size,
                              hipStream_t stream) {
    const float* x  = (const float*)d_in[0];
    const float* Wq = (const float*)d_in[1];
    const float* bq = (const float*)d_in[2];
    const float* Wk = (const float*)d_in[3];
    const float* bk = (const float*)d_in[4];
    const float* Wv = (const float*)d_in[5];
    const float* bv = (const float*)d_in[6];
    const float* Wo = (const float*)d_in[7];
    const float* bo = (const float*)d_in[8];
    float* out = (float*)d_out;

    const size_t per = (size_t)B_ * NH_ * T_ * HS_;  // 3,145,728
    const size_t wsz = 384 * 384;                    // 147,456
    ushort_t* xb  = (ushort_t*)d_ws;
    ushort_t* Wtq = xb + per;
    ushort_t* Wtk = Wtq + wsz;
    ushort_t* Wtv = Wtk + wsz;
    ushort_t* Wto = Wtv + wsz;
    ushort_t* Qb  = Wto + wsz;
    ushort_t* Kb  = Qb + per;
    ushort_t* Vtb = Kb + per;
    ushort_t* ctxb = Vtb + per;

    prep<<<dim3(1536 + 144), 256, 0, stream>>>(
        x, xb, Wq, Wk, Wv, Wo, Wtq, Wtk, Wtv, Wto);

    qkv_gemm<<<dim3(M_ / 128, 1152 / 128), 256, 0, stream>>>(
        xb, Wtq, Wtk, Wtv, bq, bk, bv, Qb, Kb, Vtb);

    attn_mfma<<<dim3(32, NH_, B_), 256, 0, stream>>>(Qb, Kb, Vtb, ctxb);

    proj_gemm<<<dim3(M_ / 64, 384 / 128), 256, 0, stream>>>(ctxb, Wto, bo, out);
}

// Round 8
// 143.544 us; speedup vs baseline: 1.6404x; 1.0482x over previous
//
#include <hip/hip_runtime.h>

#define B_  4
#define T_  2048
#define C_  384
#define NH_ 6
#define HS_ 64
#define M_  (B_*T_)   // 8192 rows

typedef float floatx4 __attribute__((ext_vector_type(4)));
typedef __bf16 bf16x8 __attribute__((ext_vector_type(8)));
typedef unsigned short ushort_t;
typedef unsigned short ushortx8 __attribute__((ext_vector_type(8)));
typedef unsigned short ushortx4 __attribute__((ext_vector_type(4)));

__device__ __forceinline__ ushort_t f2bf(float f) {   // RNE (epilogues)
    unsigned u = __builtin_bit_cast(unsigned, f);
    unsigned r = (u + 0x7FFFu + ((u >> 16) & 1u)) >> 16;
    return (ushort_t)r;
}
__device__ __forceinline__ ushort_t f2bf_t(float f) {  // truncate (hot loop; p in [0,1])
    return (ushort_t)(__builtin_bit_cast(unsigned, f) >> 16);
}

// ---------------------------------------------------------------------------
// prep: x fp32->bf16 cast (blocks [0,1536)) + W transpose-casts ([1536,1680)).
// ---------------------------------------------------------------------------
__global__ __launch_bounds__(256) void prep(
    const float* __restrict__ x, ushort_t* __restrict__ xb,
    const float* __restrict__ Wq, const float* __restrict__ Wk,
    const float* __restrict__ Wv, const float* __restrict__ Wo,
    ushort_t* __restrict__ Wtq, ushort_t* __restrict__ Wtk,
    ushort_t* __restrict__ Wtv, ushort_t* __restrict__ Wto)
{
    __shared__ float Ls[64][65];
    const int tid = threadIdx.x;
    const int bx = blockIdx.x;

    if (bx < 1536) {
        const int i = (bx * 256 + tid) * 8;
        const float4 a = *(const float4*)&x[i];
        const float4 b = *(const float4*)&x[i + 4];
        ushortx8 p;
        p[0] = f2bf(a.x); p[1] = f2bf(a.y); p[2] = f2bf(a.z); p[3] = f2bf(a.w);
        p[4] = f2bf(b.x); p[5] = f2bf(b.y); p[6] = f2bf(b.z); p[7] = f2bf(b.w);
        *(ushortx8*)&xb[i] = p;
        return;
    }

    const int idx = bx - 1536;
    const int z = idx / 36, rest = idx % 36;
    const float* __restrict__ W = (z == 0) ? Wq : (z == 1) ? Wk : (z == 2) ? Wv : Wo;
    ushort_t* __restrict__ Wt   = (z == 0) ? Wtq : (z == 1) ? Wtk : (z == 2) ? Wtv : Wto;
    const int k0 = (rest / 6) * 64, n0 = (rest % 6) * 64;

    #pragma unroll
    for (int p = 0; p < 4; ++p) {
        const int kk = p * 16 + (tid >> 4);
        const int nn = (tid & 15) * 4;
        const float4 v = *(const float4*)&W[(size_t)(k0 + kk) * 384 + n0 + nn];
        Ls[kk][nn] = v.x; Ls[kk][nn + 1] = v.y; Ls[kk][nn + 2] = v.z; Ls[kk][nn + 3] = v.w;
    }
    __syncthreads();
    #pragma unroll
    for (int p = 0; p < 4; ++p) {
        const int n = p * 16 + (tid >> 4);
        const int kc = (tid & 15) * 4;
        ushortx4 pk;
        #pragma unroll
        for (int t = 0; t < 4; ++t) pk[t] = f2bf(Ls[kc + t][n]);
        *(ushortx4*)&Wt[(size_t)(n0 + n) * 384 + k0 + kc] = pk;
    }
}

// ---------------------------------------------------------------------------
// Fused QKV MFMA GEMM, BM=64(t) x BN=128(n): grid (128, 9) = 1152 blocks.
// Single-barrier pipeline, double-buffered swizzled LDS.
// Q/K: D[row=n][col=t]; V: D[row=t][col=n]  (operand-swap per output layout).
// ---------------------------------------------------------------------------
__global__ __launch_bounds__(256) void qkv_gemm(
    const ushort_t* __restrict__ xb,
    const ushort_t* __restrict__ Wtq, const ushort_t* __restrict__ Wtk,
    const ushort_t* __restrict__ Wtv,
    const float* __restrict__ bq, const float* __restrict__ bk, const float* __restrict__ bv,
    ushort_t* __restrict__ Qb, ushort_t* __restrict__ Kb, ushort_t* __restrict__ Vtb)
{
    __shared__ ushort_t Sm[2][6144];   // [buf][ x 64x32 = 2048 | W 128x32 = 4096 ]

    const int tid  = threadIdx.x;
    const int lane = tid & 63;
    const int wv   = tid >> 6;
    const int m    = lane & 15;
    const int quad = lane >> 4;

    const int t0 = blockIdx.x * 64;
    const int n0 = blockIdx.y * 128;
    const int which = n0 / 384;
    const int n_in0 = n0 % 384;
    const bool isV = (which == 2);

    const ushort_t* __restrict__ Wt = (which == 0) ? Wtq : (which == 1) ? Wtk : Wtv;

    const int tg0 = (wv & 1) * 32;     // wave's t-row group (within 64)
    const int ng0 = (wv >> 1) * 64;    // wave's n-row group (within 128)

    // staging coords
    const int rX = tid >> 2, cX = tid & 3;
    const int swX = ((cX ^ ((rX >> 1) & 3)) << 3);
    const int rW0 = tid >> 2, rW1 = rW0 + 64, cW = tid & 3;
    const int swW = ((cW ^ ((rW0 >> 1) & 3)) << 3);   // (rW1>>1)&3 == (rW0>>1)&3

    floatx4 acc[8];
    #pragma unroll
    for (int i = 0; i < 8; ++i) acc[i] = (floatx4){0.f, 0.f, 0.f, 0.f};

    ushortx8 xr  = *(const ushortx8*)&xb[(size_t)(t0 + rX) * 384 + cX * 8];
    ushortx8 wr0 = *(const ushortx8*)&Wt[(size_t)(n_in0 + rW0) * 384 + cW * 8];
    ushortx8 wr1 = *(const ushortx8*)&Wt[(size_t)(n_in0 + rW1) * 384 + cW * 8];

    for (int ks = 0; ks < 12; ++ks) {
        ushort_t* __restrict__ S = &Sm[ks & 1][0];
        *(ushortx8*)&S[rX * 32 + swX] = xr;
        *(ushortx8*)&S[2048 + rW0 * 32 + swW] = wr0;
        *(ushortx8*)&S[2048 + rW1 * 32 + swW] = wr1;
        __syncthreads();

        if (ks < 11) {
            const int kk = (ks + 1) * 32;
            xr  = *(const ushortx8*)&xb[(size_t)(t0 + rX) * 384 + kk + cX * 8];
            wr0 = *(const ushortx8*)&Wt[(size_t)(n_in0 + rW0) * 384 + kk + cW * 8];
            wr1 = *(const ushortx8*)&Wt[(size_t)(n_in0 + rW1) * 384 + kk + cW * 8];
        }

        bf16x8 fX[2], fW[4];
        #pragma unroll
        for (int i = 0; i < 2; ++i) {
            const int r = tg0 + i * 16 + m;
            fX[i] = *(const bf16x8*)&S[r * 32 + ((quad ^ ((r >> 1) & 3)) << 3)];
        }
        #pragma unroll
        for (int i = 0; i < 4; ++i) {
            const int r = ng0 + i * 16 + m;
            fW[i] = *(const bf16x8*)&S[2048 + r * 32 + ((quad ^ ((r >> 1) & 3)) << 3)];
        }
        if (isV) {
            #pragma unroll
            for (int i = 0; i < 2; ++i)
                #pragma unroll
                for (int j = 0; j < 4; ++j)
                    acc[i * 4 + j] = __builtin_amdgcn_mfma_f32_16x16x32_bf16(fX[i], fW[j], acc[i * 4 + j], 0, 0, 0);
        } else {
            #pragma unroll
            for (int i = 0; i < 4; ++i)
                #pragma unroll
                for (int j = 0; j < 2; ++j)
                    acc[i * 2 + j] = __builtin_amdgcn_mfma_f32_16x16x32_bf16(fW[i], fX[j], acc[i * 2 + j], 0, 0, 0);
        }
    }

    if (!isV) {
        ushort_t* __restrict__ out = (which == 0) ? Qb : Kb;
        const float* __restrict__ bias = (which == 0) ? bq : bk;
        const float scale = (which == 0) ? 0.125f : 1.0f;
        #pragma unroll
        for (int i = 0; i < 4; ++i) {
            const int n_base = n_in0 + ng0 + i * 16 + quad * 4;
            const int h = n_base >> 6, d0 = n_base & 63;
            #pragma unroll
            for (int j = 0; j < 2; ++j) {
                const int tg = t0 + tg0 + j * 16 + m;
                const int b = tg >> 11, tb = tg & (T_ - 1);
                ushortx4 pk;
                #pragma unroll
                for (int r = 0; r < 4; ++r)
                    pk[r] = f2bf((acc[i * 2 + j][r] + bias[n_base + r]) * scale);
                *(ushortx4*)&out[(((size_t)(b * NH_ + h)) * T_ + tb) * HS_ + d0] = pk;
            }
        }
    } else {
        #pragma unroll
        for (int i = 0; i < 2; ++i) {
            const int tgq = t0 + tg0 + i * 16 + quad * 4;
            const int b = tgq >> 11, tb0 = tgq & (T_ - 1);
            #pragma unroll
            for (int j = 0; j < 4; ++j) {
                const int n_l = n_in0 + ng0 + j * 16 + m;
                const int h = n_l >> 6, d = n_l & 63;
                const float bb = bv[n_l];
                ushortx4 pk;
                #pragma unroll
                for (int r = 0; r < 4; ++r) pk[r] = f2bf(acc[i * 4 + j][r] + bb);
                *(ushortx4*)&Vtb[(((size_t)(b * NH_ + h)) * HS_ + d) * T_ + tb0] = pk;
            }
        }
    }
}

// ---------------------------------------------------------------------------
// Output projection, BM=64(t) x BN=64(n): grid (128, 6) = 768 blocks (3/CU).
// A = Wto rows (n), B = ctx rows (t) -> float4 stores.
// ---------------------------------------------------------------------------
__global__ __launch_bounds__(256) void proj_gemm(
    const ushort_t* __restrict__ ctxb,
    const ushort_t* __restrict__ Wto,
    const float* __restrict__ bo,
    float* __restrict__ out)
{
    __shared__ ushort_t Sm[2][4096];   // [buf][ ctx 64x32 | W 64x32 ]

    const int tid  = threadIdx.x;
    const int lane = tid & 63;
    const int wv   = tid >> 6;
    const int m    = lane & 15;
    const int quad = lane >> 4;

    const int t0 = blockIdx.x * 64;
    const int n0 = blockIdx.y * 64;
    const int tg0 = (wv & 1) * 32;
    const int ng0 = (wv >> 1) * 32;

    const int rC = tid >> 2, cC = tid & 3;
    const int swC = ((cC ^ ((rC >> 1) & 3)) << 3);

    floatx4 acc[2][2];
    #pragma unroll
    for (int i = 0; i < 2; ++i)
        #pragma unroll
        for (int j = 0; j < 2; ++j) acc[i][j] = (floatx4){0.f, 0.f, 0.f, 0.f};

    ushortx8 cr = *(const ushortx8*)&ctxb[(size_t)(t0 + rC) * 384 + cC * 8];
    ushortx8 wr = *(const ushortx8*)&Wto[(size_t)(n0 + rC) * 384 + cC * 8];

    for (int ks = 0; ks < 12; ++ks) {
        ushort_t* __restrict__ S = &Sm[ks & 1][0];
        *(ushortx8*)&S[rC * 32 + swC] = cr;
        *(ushortx8*)&S[2048 + rC * 32 + swC] = wr;
        __syncthreads();

        if (ks < 11) {
            const int kk = (ks + 1) * 32;
            cr = *(const ushortx8*)&ctxb[(size_t)(t0 + rC) * 384 + kk + cC * 8];
            wr = *(const ushortx8*)&Wto[(size_t)(n0 + rC) * 384 + kk + cC * 8];
        }

        bf16x8 fA[2], fB[2];
        #pragma unroll
        for (int i = 0; i < 2; ++i) {
            const int rn = ng0 + i * 16 + m;
            fA[i] = *(const bf16x8*)&S[2048 + rn * 32 + ((quad ^ ((rn >> 1) & 3)) << 3)];
            const int rt = tg0 + i * 16 + m;
            fB[i] = *(const bf16x8*)&S[rt * 32 + ((quad ^ ((rt >> 1) & 3)) << 3)];
        }
        #pragma unroll
        for (int i = 0; i < 2; ++i)
            #pragma unroll
            for (int j = 0; j < 2; ++j)
                acc[i][j] = __builtin_amdgcn_mfma_f32_16x16x32_bf16(fA[i], fB[j], acc[i][j], 0, 0, 0);
    }

    #pragma unroll
    for (int i = 0; i < 2; ++i) {
        const int n_base = n0 + ng0 + i * 16 + quad * 4;
        const float4 bb = *(const float4*)&bo[n_base];
        #pragma unroll
        for (int j = 0; j < 2; ++j) {
            const int tg = t0 + tg0 + j * 16 + m;
            float4 o;
            o.x = acc[i][j][0] + bb.x;
            o.y = acc[i][j][1] + bb.y;
            o.z = acc[i][j][2] + bb.z;
            o.w = acc[i][j][3] + bb.w;
            *(float4*)&out[(size_t)tg * 384 + n_base] = o;
        }
    }
}

// ---------------------------------------------------------------------------
// MFMA flash attention, UNIFORM-EXTENT blocks: block j owns q-rows
// [64j, 64j+64) as four 16-row wave-tiles -> every wave has k-extent j.
// No idle wave-iters; total block-iters 12672 (was 18816). Snake rank
// mapping balances per-CU load (3 co-resident blocks sum ~50 iters).
// Double-buffered swizzled K/V staging, one barrier/iter, prefetch after
// barrier, fixed-max softmax, truncating P-cast.
// ---------------------------------------------------------------------------
__global__ __launch_bounds__(256) void attn_mfma(
    const ushort_t* __restrict__ Q,    // [BH][T][64] bf16, pre-scaled 1/8
    const ushort_t* __restrict__ K,    // [BH][T][64] bf16
    const ushort_t* __restrict__ Vt,   // [BH][64][T] bf16
    ushort_t* __restrict__ ctx)        // [B][T][C] bf16
{
    __shared__ ushort_t Ks[2][64 * 64];
    __shared__ ushort_t Vs[2][64 * 64];
    __shared__ ushort_t Ps[4][16 * 64];

    const int tid  = threadIdx.x;
    const int lane = tid & 63;
    const int wv   = tid >> 6;
    const int m    = lane & 15;
    const int quad = lane >> 4;
    const int cA   = (quad ^ (m & 7)) << 3;

    // snake rank mapping: balance per-CU block-length sums under round-robin
    const int flat = blockIdx.x + 32 * (blockIdx.y + 6 * blockIdx.z);  // 0..767
    const int rr = flat >> 8, ss = flat & 255;
    const int rank = (rr << 8) + ((rr & 1) ? (255 - ss) : ss);
    const int j   = 31 - (rank / 24);          // 32 lengths x 24 bh, longest at rank 0
    const int idx = rank % 24;
    const int bh  = idx;                        // [b*6+h] flattened
    const int b   = idx / 6, h = idx % 6;

    const int rowbase = j * 64 + wv * 16;       // all waves: extent = j
    const int ext = j;

    const ushort_t* __restrict__ Kg = K  + (size_t)bh * (T_ * HS_);
    const ushort_t* __restrict__ Vg = Vt + (size_t)bh * (HS_ * T_);

    const int r0 = tid >> 3,         c0 = tid & 7;
    const int r1 = (tid + 256) >> 3, c1 = tid & 7;
    const int sw0 = ((c0 ^ (r0 & 7)) << 3);
    const int sw1 = ((c1 ^ (r1 & 7)) << 3);

    bf16x8 qf0, qf1;
    {
        const ushort_t* qp = Q + ((size_t)bh * T_ + rowbase + m) * HS_;
        qf0 = *(const bf16x8*)(qp + quad * 8);
        qf1 = *(const bf16x8*)(qp + 32 + quad * 8);
    }

    floatx4 acc_o[4];
    #pragma unroll
    for (int dt = 0; dt < 4; ++dt) acc_o[dt] = (floatx4){0.f, 0.f, 0.f, 0.f};
    float l_lane[4] = {0.f, 0.f, 0.f, 0.f};

    ushort_t* __restrict__ Pw = &Ps[wv][0];

    ushortx8 kr0 = *(const ushortx8*)&Kg[(size_t)r0 * HS_ + c0 * 8];
    ushortx8 kr1 = *(const ushortx8*)&Kg[(size_t)r1 * HS_ + c1 * 8];
    ushortx8 vr0 = *(const ushortx8*)&Vg[(size_t)r0 * T_ + c0 * 8];
    ushortx8 vr1 = *(const ushortx8*)&Vg[(size_t)r1 * T_ + c1 * 8];

    for (int kt = 0; kt <= ext; ++kt) {
        ushort_t* __restrict__ Kc = &Ks[kt & 1][0];
        ushort_t* __restrict__ Vc = &Vs[kt & 1][0];
        *(ushortx8*)&Kc[r0 * 64 + sw0] = kr0;
        *(ushortx8*)&Kc[r1 * 64 + sw1] = kr1;
        *(ushortx8*)&Vc[r0 * 64 + sw0] = vr0;
        *(ushortx8*)&Vc[r1 * 64 + sw1] = vr1;
        __syncthreads();

        if (kt < ext) {   // prefetch after barrier; hides under compute
            const int s1 = (kt + 1) * 64;
            kr0 = *(const ushortx8*)&Kg[(size_t)(s1 + r0) * HS_ + c0 * 8];
            kr1 = *(const ushortx8*)&Kg[(size_t)(s1 + r1) * HS_ + c1 * 8];
            vr0 = *(const ushortx8*)&Vg[(size_t)r0 * T_ + s1 + c0 * 8];
            vr1 = *(const ushortx8*)&Vg[(size_t)r1 * T_ + s1 + c1 * 8];
        }

        // ---- S = Q K^T ----
        floatx4 s[4];
        #pragma unroll
        for (int kc = 0; kc < 4; ++kc) {
            const int kb = (kc * 16 + m) * 64;
            bf16x8 k0 = *(const bf16x8*)&Kc[kb + cA];
            bf16x8 k1 = *(const bf16x8*)&Kc[kb + (cA ^ 32)];
            floatx4 a = (floatx4){0.f, 0.f, 0.f, 0.f};
            a = __builtin_amdgcn_mfma_f32_16x16x32_bf16(qf0, k0, a, 0, 0, 0);
            a = __builtin_amdgcn_mfma_f32_16x16x32_bf16(qf1, k1, a, 0, 0, 0);
            s[kc] = a;
        }

        if (kt == ext) {   // diagonal 64-key tile: causal mask
            #pragma unroll
            for (int kc = 0; kc < 4; ++kc) {
                const int key = kt * 64 + kc * 16 + m;
                #pragma unroll
                for (int r = 0; r < 4; ++r)
                    if (key > rowbase + quad * 4 + r) s[kc][r] = -1e30f;
            }
        }

        // ---- fixed-max softmax; truncating P-cast; P -> per-wave LDS ----
        const int mc = m >> 3, mp = m & 7;
        #pragma unroll
        for (int r = 0; r < 4; ++r) {
            const int prow = quad * 4 + r;
            const int psw = prow & 7;
            const float p0 = __expf(s[0][r]);
            const float p1 = __expf(s[1][r]);
            const float p2 = __expf(s[2][r]);
            const float p3 = __expf(s[3][r]);
            l_lane[r] += (p0 + p1) + (p2 + p3);
            const int pb = prow * 64 + mp;
            Pw[pb + (((0 + mc) ^ psw) << 3)] = f2bf_t(p0);
            Pw[pb + (((2 + mc) ^ psw) << 3)] = f2bf_t(p1);
            Pw[pb + (((4 + mc) ^ psw) << 3)] = f2bf_t(p2);
            Pw[pb + (((6 + mc) ^ psw) << 3)] = f2bf_t(p3);
        }
        asm volatile("s_waitcnt lgkmcnt(0)" ::: "memory");
        bf16x8 pf0 = *(const bf16x8*)&Pw[m * 64 + cA];
        bf16x8 pf1 = *(const bf16x8*)&Pw[m * 64 + (cA ^ 32)];

        // ---- O += P V ----
        #pragma unroll
        for (int dt = 0; dt < 4; ++dt) {
            const int vb = (dt * 16 + m) * 64;
            bf16x8 v0 = *(const bf16x8*)&Vc[vb + cA];
            bf16x8 v1 = *(const bf16x8*)&Vc[vb + (cA ^ 32)];
            acc_o[dt] = __builtin_amdgcn_mfma_f32_16x16x32_bf16(pf0, v0, acc_o[dt], 0, 0, 0);
            acc_o[dt] = __builtin_amdgcn_mfma_f32_16x16x32_bf16(pf1, v1, acc_o[dt], 0, 0, 0);
        }
    }

    // epilogue
    float l[4];
    #pragma unroll
    for (int r = 0; r < 4; ++r) {
        float ls = l_lane[r];
        ls += __shfl_xor(ls, 1, 64);
        ls += __shfl_xor(ls, 2, 64);
        ls += __shfl_xor(ls, 4, 64);
        ls += __shfl_xor(ls, 8, 64);
        l[r] = ls;
    }
    #pragma unroll
    for (int dt = 0; dt < 4; ++dt) {
        #pragma unroll
        for (int r = 0; r < 4; ++r) {
            const int t = rowbase + quad * 4 + r;
            ctx[((size_t)(b * T_) + t) * C_ + h * HS_ + dt * 16 + m] =
                f2bf(acc_o[dt][r] / l[r]);
        }
    }
}

// ---------------------------------------------------------------------------
// Launcher. ws (ushorts): xb | Wtq|Wtk|Wtv|Wto | Q | K | Vt | ctx  (~32 MB)
// ---------------------------------------------------------------------------
extern "C" void kernel_launch(void* const* d_in, const int* in_sizes, int n_in,
                              void* d_out, int out_size, void* d_ws, size_t ws_size,
                              hipStream_t stream) {
    const float* x  = (const float*)d_in[0];
    const float* Wq = (const float*)d_in[1];
    const float* bq = (const float*)d_in[2];
    const float* Wk = (const float*)d_in[3];
    const float* bk = (const float*)d_in[4];
    const float* Wv = (const float*)d_in[5];
    const float* bv = (const float*)d_in[6];
    const float* Wo = (const float*)d_in[7];
    const float* bo = (const float*)d_in[8];
    float* out = (float*)d_out;

    const size_t per = (size_t)B_ * NH_ * T_ * HS_;  // 3,145,728
    const size_t wsz = 384 * 384;                    // 147,456
    ushort_t* xb  = (ushort_t*)d_ws;
    ushort_t* Wtq = xb + per;
    ushort_t* Wtk = Wtq + wsz;
    ushort_t* Wtv = Wtk + wsz;
    ushort_t* Wto = Wtv + wsz;
    ushort_t* Qb  = Wto + wsz;
    ushort_t* Kb  = Qb + per;
    ushort_t* Vtb = Kb + per;
    ushort_t* ctxb = Vtb + per;

    prep<<<dim3(1536 + 144), 256, 0, stream>>>(
        x, xb, Wq, Wk, Wv, Wo, Wtq, Wtk, Wtv, Wto);

    qkv_gemm<<<dim3(M_ / 64, 1152 / 128), 256, 0, stream>>>(
        xb, Wtq, Wtk, Wtv, bq, bk, bv, Qb, Kb, Vtb);

    attn_mfma<<<dim3(32, NH_, B_), 256, 0, stream>>>(Qb, Kb, Vtb, ctxb);

    proj_gemm<<<dim3(M_ / 64, 384 / 64), 256, 0, stream>>>(ctxb, Wto, bo, out);
}